// Round 1
// baseline (377.138 us; speedup 1.0000x reference)
//
#include <hip/hip_runtime.h>
#include <hip/hip_bf16.h>
#include <float.h>

// ---------------------------------------------------------------------------
// Problem: StageJointExpertRouter
//   x   [32768,1024] f32
//   w1  [1024,256]   f32, b1 [256]
//   w2  [256,64]     f32, b2 [64]
//   top_k (int scalar, =8)
// Outputs (concat in d_out, f32): logits [N,64], masked [N,64], probs [N,64]
// ---------------------------------------------------------------------------

#define N_ROWS 32768
#define D_IN   1024
#define D_H    256
#define N_E    64
#define NEG_INF_VAL (-1000000000.0f)

// ======================= Kernel 1: h = relu(x@w1 + b1) =====================
// Tile: BM=128, BN=64, BK=16; 256 threads; per-thread 8x4 micro-tile.
#define BM 128
#define BN 64
#define BK 16

__global__ __launch_bounds__(256) void gemm1_relu_kernel(
    const float* __restrict__ x, const float* __restrict__ w1,
    const float* __restrict__ b1, float* __restrict__ h) {
  __shared__ float As[BK][BM];  // k-major for contiguous fragment reads
  __shared__ float Bs[BK][BN];

  const int t  = threadIdx.x;
  const int tx = t & 15;   // 16 cols of threads -> 64 output cols
  const int ty = t >> 4;   // 16 rows of threads -> 128 output rows
  const int m0 = blockIdx.y * BM;
  const int n0 = blockIdx.x * BN;

  float acc[8][4];
#pragma unroll
  for (int i = 0; i < 8; ++i)
#pragma unroll
    for (int j = 0; j < 4; ++j) acc[i][j] = 0.0f;

  // A-load indexing: 128 rows x 16 cols; 256 threads load 2 float4 each.
  const int ar  = t >> 2;          // 0..63
  const int ac4 = (t & 3) * 4;     // 0,4,8,12
  // B-load indexing: 16 rows x 64 cols; 256 threads load 1 float4 each.
  const int br  = t >> 4;          // 0..15
  const int bc4 = (t & 15) * 4;    // 0..60

  for (int k0 = 0; k0 < D_IN; k0 += BK) {
    // ---- stage A tile (transposed into k-major) ----
#pragma unroll
    for (int p = 0; p < 2; ++p) {
      const int rr = ar + p * 64;
      const float4 v =
          *(const float4*)(x + (size_t)(m0 + rr) * D_IN + k0 + ac4);
      As[ac4 + 0][rr] = v.x;
      As[ac4 + 1][rr] = v.y;
      As[ac4 + 2][rr] = v.z;
      As[ac4 + 3][rr] = v.w;
    }
    // ---- stage B tile ----
    *(float4*)&Bs[br][bc4] =
        *(const float4*)(w1 + (size_t)(k0 + br) * D_H + n0 + bc4);
    __syncthreads();

#pragma unroll
    for (int kk = 0; kk < BK; ++kk) {
      const float4 a0 = *(const float4*)&As[kk][ty * 8];
      const float4 a1 = *(const float4*)&As[kk][ty * 8 + 4];
      const float4 b0 = *(const float4*)&Bs[kk][tx * 4];
      const float a[8] = {a0.x, a0.y, a0.z, a0.w, a1.x, a1.y, a1.z, a1.w};
      const float b[4] = {b0.x, b0.y, b0.z, b0.w};
#pragma unroll
      for (int i = 0; i < 8; ++i)
#pragma unroll
        for (int j = 0; j < 4; ++j) acc[i][j] += a[i] * b[j];
    }
    __syncthreads();
  }

  // epilogue: + b1, ReLU, store
  const float4 bv = *(const float4*)(b1 + n0 + tx * 4);
#pragma unroll
  for (int i = 0; i < 8; ++i) {
    const int m = m0 + ty * 8 + i;
    float4 o;
    o.x = fmaxf(acc[i][0] + bv.x, 0.0f);
    o.y = fmaxf(acc[i][1] + bv.y, 0.0f);
    o.z = fmaxf(acc[i][2] + bv.z, 0.0f);
    o.w = fmaxf(acc[i][3] + bv.w, 0.0f);
    *(float4*)(h + (size_t)m * D_H + n0 + tx * 4) = o;
  }
}

// ====== Kernel 2: logits = h@w2+b2; top-k mask; softmax; write all 3 =======
// 256 threads = 4 waves; one row per wave; lane = expert index.
__global__ __launch_bounds__(256) void router_kernel(
    const float* __restrict__ h, const float* __restrict__ w2,
    const float* __restrict__ b2, const int* __restrict__ topk_p,
    float* __restrict__ out_logits, float* __restrict__ out_masked,
    float* __restrict__ out_probs) {
  __shared__ float w2l[D_H * N_E];  // 64 KB

  const int t = threadIdx.x;
  // stage w2 into LDS (coalesced float4)
#pragma unroll
  for (int i = 0; i < 16; ++i) {
    const int idx = (i * 256 + t) * 4;
    *(float4*)&w2l[idx] = *(const float4*)(w2 + idx);
  }
  __syncthreads();

  const int wid  = t >> 6;
  const int lane = t & 63;
  const int row  = blockIdx.x * 4 + wid;

  // ---- logits[lane] = sum_k h[row][k] * w2[k][lane] + b2[lane] ----
  float acc = b2[lane];
  const float* hrow = h + (size_t)row * D_H;
#pragma unroll 8
  for (int k4 = 0; k4 < D_H / 4; ++k4) {
    const float4 hv = *(const float4*)(hrow + k4 * 4);  // wave-uniform
    acc += hv.x * w2l[(k4 * 4 + 0) * N_E + lane];
    acc += hv.y * w2l[(k4 * 4 + 1) * N_E + lane];
    acc += hv.z * w2l[(k4 * 4 + 2) * N_E + lane];
    acc += hv.w * w2l[(k4 * 4 + 3) * N_E + lane];
  }

  const float logit = acc;  // TEMPERATURE == 1.0
  out_logits[(size_t)row * N_E + lane] = logit;

  // ---- top-k selection (argmax k times, min-index tie-break) ----
  int K = topk_p[0];
  const bool doMask = (K > 0 && K < N_E);
  int sel = doMask ? 0 : 1;
  float cur = logit;
  if (doMask) {
    for (int it = 0; it < K; ++it) {
      float m  = cur;
      int   mi = lane;
#pragma unroll
      for (int off = 32; off > 0; off >>= 1) {
        const float om = __shfl_xor(m, off);
        const int   oi = __shfl_xor(mi, off);
        if (om > m || (om == m && oi < mi)) {
          m  = om;
          mi = oi;
        }
      }
      if (lane == mi) {
        sel = 1;
        cur = -FLT_MAX;
      }
    }
  }
  const float masked = sel ? logit : NEG_INF_VAL;
  out_masked[(size_t)row * N_E + lane] = masked;

  // ---- softmax over masked ----
  float mx = masked;
#pragma unroll
  for (int off = 32; off > 0; off >>= 1) mx = fmaxf(mx, __shfl_xor(mx, off));
  float e = __expf(masked - mx);
  // exp(-1e9 - mx) underflows to 0, matching reference softmax numerically
  float s = e;
#pragma unroll
  for (int off = 32; off > 0; off >>= 1) s += __shfl_xor(s, off);
  out_probs[(size_t)row * N_E + lane] = e / s;
}

// ============================== launcher ===================================
extern "C" void kernel_launch(void* const* d_in, const int* in_sizes, int n_in,
                              void* d_out, int out_size, void* d_ws,
                              size_t ws_size, hipStream_t stream) {
  const float* x  = (const float*)d_in[0];
  const float* w1 = (const float*)d_in[1];
  const float* b1 = (const float*)d_in[2];
  const float* w2 = (const float*)d_in[3];
  const float* b2 = (const float*)d_in[4];
  const int* topk = (const int*)d_in[5];

  float* h = (float*)d_ws;  // [N_ROWS, D_H] f32 = 33.5 MB

  float* out_logits = (float*)d_out;
  float* out_masked = out_logits + (size_t)N_ROWS * N_E;
  float* out_probs  = out_masked + (size_t)N_ROWS * N_E;

  dim3 grid1(D_H / BN, N_ROWS / BM);  // (4, 256)
  gemm1_relu_kernel<<<grid1, 256, 0, stream>>>(x, w1, b1, h);

  router_kernel<<<N_ROWS / 4, 256, 0, stream>>>(h, w2, b2, topk, out_logits,
                                                out_masked, out_probs);
}

// Round 2
// 219.534 us; speedup vs baseline: 1.7179x; 1.7179x over previous
//
#include <hip/hip_runtime.h>
#include <hip/hip_bf16.h>
#include <float.h>

// ---------------------------------------------------------------------------
// StageJointExpertRouter: h = relu(x@w1+b1); logits = h@w2+b2; top-k mask;
// softmax.  x [32768,1024] f32, w1 [1024,256], w2 [256,64].
// Outputs concat f32: logits [N,64], masked [N,64], probs [N,64].
//
// GEMM1 uses split-fp16 MFMA (xh*wh + xh*wl + xl*wh, f32 accum): fp16 2-term
// split keeps ~2^-24 relative operand error, so logits deviate from the f32
// reference only at f32-accumulation-rounding level (~2e-6) -> top-k safe.
// ---------------------------------------------------------------------------

#define N_ROWS 32768
#define D_IN   1024
#define D_H    256
#define N_E    64
#define NEG_INF_VAL (-1000000000.0f)

typedef _Float16 f16x8 __attribute__((ext_vector_type(8)));
typedef float    f32x16 __attribute__((ext_vector_type(16)));

// ================= Kernel 0: split w1 -> whT, wlT (fp16, transposed) =======
// w1[k][n] f32  ->  whT[n][k], wlT[n][k] fp16  (transposed so GEMM B-staging
// reads contiguous k-runs per output column).
__global__ __launch_bounds__(256) void split_w1_kernel(
    const float* __restrict__ w1, _Float16* __restrict__ whT,
    _Float16* __restrict__ wlT) {
  const int idx = blockIdx.x * 256 + threadIdx.x;  // 0 .. 262143
  const int k = idx >> 8;    // row of w1
  const int n = idx & 255;   // col of w1
  const float v = w1[idx];
  const _Float16 hi = (_Float16)v;
  const _Float16 lo = (_Float16)(v - (float)hi);
  whT[n * D_IN + k] = hi;
  wlT[n * D_IN + k] = lo;
}

// ============== Kernel 1: h = relu(x@w1+b1) via split-fp16 MFMA ============
// Tile 128x128, BK=32, 512 threads (8 waves as 2x4 of 64x32 per-wave tiles).
// LDS (32 KB): Ah[128][32]f16 @0, Al @8K, Bh[128cols][32k] @16K, Bl @24K.
// 64-byte rows, XOR swizzle: kbyte ^= (row&3)<<4  (8-access/bank floor).
#define BM 128
#define BN 128
#define BK 32

__global__ __launch_bounds__(512) void gemm1_mfma_kernel(
    const float* __restrict__ x, const _Float16* __restrict__ whT,
    const _Float16* __restrict__ wlT, const float* __restrict__ b1,
    float* __restrict__ h) {
  __shared__ char lds[32768];

  const int t = threadIdx.x;

  // XCD-aware mapping: 512 blocks, 8 XCDs; the two N-blocks of an M-panel
  // run on the same XCD so the second read of that x panel is an L2 hit.
  const int b    = blockIdx.x;
  const int xcd  = b & 7;
  const int c    = b >> 3;                 // 0..63 within XCD
  const int m0   = (xcd * 32 + (c >> 1)) * BM;
  const int n0   = (c & 1) * BN;

  // ---- staging indices ----
  const int ar   = t >> 2;                 // 0..127 (A row / B col)
  const int ac8  = (t & 3) * 8;            // k base (elements)
  const int abyte = ar * 64 + ((ac8 * 2) ^ ((ar & 3) << 4));

  // ---- fragment indices ----
  const int wid  = t >> 6;                 // 0..7
  const int lane = t & 63;
  const int wr   = wid >> 2;               // 0..1 : row half (64 rows)
  const int wc   = wid & 3;                // 0..3 : col quarter (32 cols)
  const int l31  = lane & 31;
  const int khi  = (lane >> 5) << 4;       // byte offset of lane's k-group

  const int colB = wc * 32 + l31;          // B col in tile
  const int rowA0 = wr * 64 + l31;         // A row of mf=0 fragment

  f32x16 acc[2];
#pragma unroll
  for (int i = 0; i < 16; ++i) { acc[0][i] = 0.0f; acc[1][i] = 0.0f; }

  const float*    xp0 = x   + (size_t)(m0 + ar) * D_IN + ac8;
  const _Float16* bhp0 = whT + (size_t)(n0 + ar) * D_IN + ac8;
  const _Float16* blp0 = wlT + (size_t)(n0 + ar) * D_IN + ac8;

  for (int k0 = 0; k0 < D_IN; k0 += BK) {
    // ---- stage A: load f32, split to (hi, lo) fp16, swizzled ds_write ----
    const float4 v0 = *(const float4*)(xp0 + k0);
    const float4 v1 = *(const float4*)(xp0 + k0 + 4);
    const float vv[8] = {v0.x, v0.y, v0.z, v0.w, v1.x, v1.y, v1.z, v1.w};
    f16x8 hi8, lo8;
#pragma unroll
    for (int j = 0; j < 8; ++j) {
      const _Float16 hv = (_Float16)vv[j];
      hi8[j] = hv;
      lo8[j] = (_Float16)(vv[j] - (float)hv);
    }
    *(f16x8*)(lds +         abyte) = hi8;
    *(f16x8*)(lds +  8192 + abyte) = lo8;
    // ---- stage B: already fp16, swizzled ds_write ----
    *(f16x8*)(lds + 16384 + abyte) = *(const f16x8*)(bhp0 + k0);
    *(f16x8*)(lds + 24576 + abyte) = *(const f16x8*)(blp0 + k0);
    __syncthreads();

    // ---- fragments + MFMA ----
#pragma unroll
    for (int kf = 0; kf < 2; ++kf) {
      const int kb = kf * 32 + khi;        // k byte offset within row
      const int boff = colB * 64 + (kb ^ ((colB & 3) << 4));
      const f16x8 bh_ = *(const f16x8*)(lds + 16384 + boff);
      const f16x8 bl_ = *(const f16x8*)(lds + 24576 + boff);
#pragma unroll
      for (int mf = 0; mf < 2; ++mf) {
        const int rowA = rowA0 + mf * 32;
        const int aoff = rowA * 64 + (kb ^ ((rowA & 3) << 4));
        const f16x8 ah_ = *(const f16x8*)(lds +        aoff);
        const f16x8 al_ = *(const f16x8*)(lds + 8192 + aoff);
        acc[mf] = __builtin_amdgcn_mfma_f32_32x32x16_f16(al_, bh_, acc[mf], 0, 0, 0);
        acc[mf] = __builtin_amdgcn_mfma_f32_32x32x16_f16(ah_, bl_, acc[mf], 0, 0, 0);
        acc[mf] = __builtin_amdgcn_mfma_f32_32x32x16_f16(ah_, bh_, acc[mf], 0, 0, 0);
      }
    }
    __syncthreads();
  }

  // ---- epilogue: + b1, ReLU, store ----
  // C/D layout (32x32): col = lane&31, row = (r&3) + 8*(r>>2) + 4*(lane>>5)
  const int colg = n0 + colB;
  const float bias = b1[colg];
#pragma unroll
  for (int mf = 0; mf < 2; ++mf) {
#pragma unroll
    for (int r = 0; r < 16; ++r) {
      const int row = (r & 3) + 8 * (r >> 2) + 4 * (lane >> 5);
      const int mg = m0 + wr * 64 + mf * 32 + row;
      h[(size_t)mg * D_H + colg] = fmaxf(acc[mf][r] + bias, 0.0f);
    }
  }
}

// ====== Kernel 2: logits = h@w2+b2; top-k mask; softmax; write all 3 =======
// 512 blocks x 256 threads (4 waves). w2 staged once per block; each wave
// processes 16 rows. lane = expert index.
__global__ __launch_bounds__(256) void router_kernel(
    const float* __restrict__ h, const float* __restrict__ w2,
    const float* __restrict__ b2, const int* __restrict__ topk_p,
    float* __restrict__ out_logits, float* __restrict__ out_masked,
    float* __restrict__ out_probs) {
  __shared__ float w2l[D_H * N_E];  // 64 KB

  const int t = threadIdx.x;
#pragma unroll
  for (int i = 0; i < 16; ++i) {
    const int idx = (i * 256 + t) * 4;
    *(float4*)&w2l[idx] = *(const float4*)(w2 + idx);
  }
  __syncthreads();

  const int wid  = t >> 6;
  const int lane = t & 63;
  const int K = topk_p[0];
  const bool doMask = (K > 0 && K < N_E);
  const float bias = b2[lane];

  for (int it = 0; it < 16; ++it) {
    const int row = blockIdx.x * 64 + it * 4 + wid;

    float acc = bias;
    const float* hrow = h + (size_t)row * D_H;
#pragma unroll 8
    for (int k4 = 0; k4 < D_H / 4; ++k4) {
      const float4 hv = *(const float4*)(hrow + k4 * 4);  // wave-uniform
      acc += hv.x * w2l[(k4 * 4 + 0) * N_E + lane];
      acc += hv.y * w2l[(k4 * 4 + 1) * N_E + lane];
      acc += hv.z * w2l[(k4 * 4 + 2) * N_E + lane];
      acc += hv.w * w2l[(k4 * 4 + 3) * N_E + lane];
    }

    const float logit = acc;  // TEMPERATURE == 1.0
    out_logits[(size_t)row * N_E + lane] = logit;

    // top-k selection (argmax K times, min-index tie-break = lax.top_k)
    int sel = doMask ? 0 : 1;
    float cur = logit;
    if (doMask) {
      for (int itk = 0; itk < K; ++itk) {
        float m  = cur;
        int   mi = lane;
#pragma unroll
        for (int off = 32; off > 0; off >>= 1) {
          const float om = __shfl_xor(m, off);
          const int   oi = __shfl_xor(mi, off);
          if (om > m || (om == m && oi < mi)) { m = om; mi = oi; }
        }
        if (lane == mi) { sel = 1; cur = -FLT_MAX; }
      }
    }
    const float masked = sel ? logit : NEG_INF_VAL;
    out_masked[(size_t)row * N_E + lane] = masked;

    // softmax over masked (exp(-1e9-mx) underflows to 0, matching ref)
    float mx = masked;
#pragma unroll
    for (int off = 32; off > 0; off >>= 1) mx = fmaxf(mx, __shfl_xor(mx, off));
    const float e = __expf(masked - mx);
    float s = e;
#pragma unroll
    for (int off = 32; off > 0; off >>= 1) s += __shfl_xor(s, off);
    out_probs[(size_t)row * N_E + lane] = e / s;
  }
}

// ============================== launcher ===================================
extern "C" void kernel_launch(void* const* d_in, const int* in_sizes, int n_in,
                              void* d_out, int out_size, void* d_ws,
                              size_t ws_size, hipStream_t stream) {
  const float* x  = (const float*)d_in[0];
  const float* w1 = (const float*)d_in[1];
  const float* b1 = (const float*)d_in[2];
  const float* w2 = (const float*)d_in[3];
  const float* b2 = (const float*)d_in[4];
  const int* topk = (const int*)d_in[5];

  char* ws = (char*)d_ws;
  _Float16* whT = (_Float16*)(ws);                    // 512 KB
  _Float16* wlT = (_Float16*)(ws + 524288);           // 512 KB
  float*    hbuf = (float*)(ws + 1048576);            // 33.5 MB

  float* out_logits = (float*)d_out;
  float* out_masked = out_logits + (size_t)N_ROWS * N_E;
  float* out_probs  = out_masked + (size_t)N_ROWS * N_E;

  split_w1_kernel<<<(D_IN * D_H) / 256, 256, 0, stream>>>(w1, whT, wlT);

  gemm1_mfma_kernel<<<(N_ROWS / BM) * (D_H / BN), 512, 0, stream>>>(
      x, whT, wlT, b1, hbuf);

  router_kernel<<<N_ROWS / 64, 256, 0, stream>>>(hbuf, w2, b2, topk,
                                                 out_logits, out_masked,
                                                 out_probs);
}

// Round 3
// 125.673 us; speedup vs baseline: 3.0009x; 1.7469x over previous
//
#include <hip/hip_runtime.h>
#include <hip/hip_bf16.h>
#include <float.h>

// ---------------------------------------------------------------------------
// StageJointExpertRouter: h = relu(x@w1+b1); logits = h@w2+b2; top-k mask;
// softmax.  x [32768,1024] f32, w1 [1024,256], w2 [256,64].
// Outputs concat f32: logits [N,64], masked [N,64], probs [N,64].
//
// Both GEMMs use split-fp16 MFMA (xh*wh + xh*wl + xl*wh, f32 accum):
// operand error ~2^-22 -> logit deviation stays at f32-rounding level
// (~1e-6), same class as the twice-passing f32/split kernels -> top-k safe.
// ---------------------------------------------------------------------------

#define N_ROWS 32768
#define D_IN   1024
#define D_H    256
#define N_E    64
#define NEG_INF_VAL (-1000000000.0f)

typedef _Float16 f16x8 __attribute__((ext_vector_type(8)));
typedef float    f32x4  __attribute__((ext_vector_type(4)));
typedef float    f32x16 __attribute__((ext_vector_type(16)));

// ========= Kernel 0: split w1 -> whT/wlT, w2 -> w2hT/w2lT (fp16, T) ========
__global__ __launch_bounds__(256) void split_weights_kernel(
    const float* __restrict__ w1, const float* __restrict__ w2,
    _Float16* __restrict__ whT, _Float16* __restrict__ wlT,
    _Float16* __restrict__ w2hT, _Float16* __restrict__ w2lT) {
  int idx = blockIdx.x * 256 + threadIdx.x;
  if (idx < D_IN * D_H) {
    const int k = idx >> 8;   // 0..1023
    const int n = idx & 255;
    const float v = w1[idx];
    const _Float16 hi = (_Float16)v;
    const _Float16 lo = (_Float16)(v - (float)hi);
    whT[n * D_IN + k] = hi;
    wlT[n * D_IN + k] = lo;
  } else {
    idx -= D_IN * D_H;        // 0..16383
    const int k = idx >> 6;   // 0..255
    const int e = idx & 63;
    const float v = w2[idx];
    const _Float16 hi = (_Float16)v;
    const _Float16 lo = (_Float16)(v - (float)hi);
    w2hT[e * D_H + k] = hi;
    w2lT[e * D_H + k] = lo;
  }
}

// ============== Kernel 1: h = relu(x@w1+b1) via split-fp16 MFMA ============
// (unchanged from R1: 128x128 tile, BK=32, 512 thr, 64x32 wave tiles)
#define BM 128
#define BN 128
#define BK 32

__global__ __launch_bounds__(512) void gemm1_mfma_kernel(
    const float* __restrict__ x, const _Float16* __restrict__ whT,
    const _Float16* __restrict__ wlT, const float* __restrict__ b1,
    float* __restrict__ h) {
  __shared__ char lds[32768];

  const int t = threadIdx.x;

  const int b    = blockIdx.x;
  const int xcd  = b & 7;
  const int c    = b >> 3;
  const int m0   = (xcd * 32 + (c >> 1)) * BM;
  const int n0   = (c & 1) * BN;

  const int ar   = t >> 2;
  const int ac8  = (t & 3) * 8;
  const int abyte = ar * 64 + ((ac8 * 2) ^ ((ar & 3) << 4));

  const int wid  = t >> 6;
  const int lane = t & 63;
  const int wr   = wid >> 2;
  const int wc   = wid & 3;
  const int l31  = lane & 31;
  const int khi  = (lane >> 5) << 4;

  const int colB = wc * 32 + l31;
  const int rowA0 = wr * 64 + l31;

  f32x16 acc[2];
#pragma unroll
  for (int i = 0; i < 16; ++i) { acc[0][i] = 0.0f; acc[1][i] = 0.0f; }

  const float*    xp0 = x   + (size_t)(m0 + ar) * D_IN + ac8;
  const _Float16* bhp0 = whT + (size_t)(n0 + ar) * D_IN + ac8;
  const _Float16* blp0 = wlT + (size_t)(n0 + ar) * D_IN + ac8;

  for (int k0 = 0; k0 < D_IN; k0 += BK) {
    const float4 v0 = *(const float4*)(xp0 + k0);
    const float4 v1 = *(const float4*)(xp0 + k0 + 4);
    const float vv[8] = {v0.x, v0.y, v0.z, v0.w, v1.x, v1.y, v1.z, v1.w};
    f16x8 hi8, lo8;
#pragma unroll
    for (int j = 0; j < 8; ++j) {
      const _Float16 hv = (_Float16)vv[j];
      hi8[j] = hv;
      lo8[j] = (_Float16)(vv[j] - (float)hv);
    }
    *(f16x8*)(lds +         abyte) = hi8;
    *(f16x8*)(lds +  8192 + abyte) = lo8;
    *(f16x8*)(lds + 16384 + abyte) = *(const f16x8*)(bhp0 + k0);
    *(f16x8*)(lds + 24576 + abyte) = *(const f16x8*)(blp0 + k0);
    __syncthreads();

#pragma unroll
    for (int kf = 0; kf < 2; ++kf) {
      const int kb = kf * 32 + khi;
      const int boff = colB * 64 + (kb ^ ((colB & 3) << 4));
      const f16x8 bh_ = *(const f16x8*)(lds + 16384 + boff);
      const f16x8 bl_ = *(const f16x8*)(lds + 24576 + boff);
#pragma unroll
      for (int mf = 0; mf < 2; ++mf) {
        const int rowA = rowA0 + mf * 32;
        const int aoff = rowA * 64 + (kb ^ ((rowA & 3) << 4));
        const f16x8 ah_ = *(const f16x8*)(lds +        aoff);
        const f16x8 al_ = *(const f16x8*)(lds + 8192 + aoff);
        acc[mf] = __builtin_amdgcn_mfma_f32_32x32x16_f16(al_, bh_, acc[mf], 0, 0, 0);
        acc[mf] = __builtin_amdgcn_mfma_f32_32x32x16_f16(ah_, bl_, acc[mf], 0, 0, 0);
        acc[mf] = __builtin_amdgcn_mfma_f32_32x32x16_f16(ah_, bh_, acc[mf], 0, 0, 0);
      }
    }
    __syncthreads();
  }

  const int colg = n0 + colB;
  const float bias = b1[colg];
#pragma unroll
  for (int mf = 0; mf < 2; ++mf) {
#pragma unroll
    for (int r = 0; r < 16; ++r) {
      const int row = (r & 3) + 8 * (r >> 2) + 4 * (lane >> 5);
      const int mg = m0 + wr * 64 + mf * 32 + row;
      h[(size_t)mg * D_H + colg] = fmaxf(acc[mf][r] + bias, 0.0f);
    }
  }
}

// ======= Kernel 2: router via MFMA, zero LDS, no barriers in k-loop ========
// 256 thr = 4 waves; wave tile = 16 rows x 64 experts (4 C-frags 16x16).
// A (h) loaded global->reg, split to fp16 hi/lo in-register.
// B (w2) pre-split fp16, loaded global->reg (32 KB, L2-hot).
// C layout (16x16x32): col = lane&15, row = (lane>>4)*4 + reg.
__global__ __launch_bounds__(256) void router_mfma_kernel(
    const float* __restrict__ h, const _Float16* __restrict__ w2hT,
    const _Float16* __restrict__ w2lT, const float* __restrict__ b2,
    const int* __restrict__ topk_p, float* __restrict__ out_logits,
    float* __restrict__ out_masked, float* __restrict__ out_probs) {
  const int t    = threadIdx.x;
  const int wid  = t >> 6;
  const int lane = t & 63;
  const int c    = lane & 15;   // A-row / B-col selector
  const int kg   = lane >> 4;   // k-group 0..3 (also C row-group)

  const int rowbase = blockIdx.x * 64 + wid * 16;

  f32x4 acc0 = {0.f, 0.f, 0.f, 0.f};
  f32x4 acc1 = {0.f, 0.f, 0.f, 0.f};
  f32x4 acc2 = {0.f, 0.f, 0.f, 0.f};
  f32x4 acc3 = {0.f, 0.f, 0.f, 0.f};

  const float*    hp  = h    + (size_t)(rowbase + c) * D_H + kg * 8;
  const _Float16* bhp = w2hT + c * D_H + kg * 8;
  const _Float16* blp = w2lT + c * D_H + kg * 8;

#pragma unroll
  for (int s = 0; s < 8; ++s) {            // K = 256 = 8 slices of 32
    const float4 a0 = *(const float4*)(hp + s * 32);
    const float4 a1 = *(const float4*)(hp + s * 32 + 4);
    const float av[8] = {a0.x, a0.y, a0.z, a0.w, a1.x, a1.y, a1.z, a1.w};
    f16x8 ah, al;
#pragma unroll
    for (int j = 0; j < 8; ++j) {
      const _Float16 hv = (_Float16)av[j];
      ah[j] = hv;
      al[j] = (_Float16)(av[j] - (float)hv);
    }
    const f16x8 bh0 = *(const f16x8*)(bhp + 0 * 16 * D_H + s * 32);
    const f16x8 bl0 = *(const f16x8*)(blp + 0 * 16 * D_H + s * 32);
    const f16x8 bh1 = *(const f16x8*)(bhp + 1 * 16 * D_H + s * 32);
    const f16x8 bl1 = *(const f16x8*)(blp + 1 * 16 * D_H + s * 32);
    const f16x8 bh2 = *(const f16x8*)(bhp + 2 * 16 * D_H + s * 32);
    const f16x8 bl2 = *(const f16x8*)(blp + 2 * 16 * D_H + s * 32);
    const f16x8 bh3 = *(const f16x8*)(bhp + 3 * 16 * D_H + s * 32);
    const f16x8 bl3 = *(const f16x8*)(blp + 3 * 16 * D_H + s * 32);
    acc0 = __builtin_amdgcn_mfma_f32_16x16x32_f16(al, bh0, acc0, 0, 0, 0);
    acc0 = __builtin_amdgcn_mfma_f32_16x16x32_f16(ah, bl0, acc0, 0, 0, 0);
    acc0 = __builtin_amdgcn_mfma_f32_16x16x32_f16(ah, bh0, acc0, 0, 0, 0);
    acc1 = __builtin_amdgcn_mfma_f32_16x16x32_f16(al, bh1, acc1, 0, 0, 0);
    acc1 = __builtin_amdgcn_mfma_f32_16x16x32_f16(ah, bl1, acc1, 0, 0, 0);
    acc1 = __builtin_amdgcn_mfma_f32_16x16x32_f16(ah, bh1, acc1, 0, 0, 0);
    acc2 = __builtin_amdgcn_mfma_f32_16x16x32_f16(al, bh2, acc2, 0, 0, 0);
    acc2 = __builtin_amdgcn_mfma_f32_16x16x32_f16(ah, bl2, acc2, 0, 0, 0);
    acc2 = __builtin_amdgcn_mfma_f32_16x16x32_f16(ah, bh2, acc2, 0, 0, 0);
    acc3 = __builtin_amdgcn_mfma_f32_16x16x32_f16(al, bh3, acc3, 0, 0, 0);
    acc3 = __builtin_amdgcn_mfma_f32_16x16x32_f16(ah, bl3, acc3, 0, 0, 0);
    acc3 = __builtin_amdgcn_mfma_f32_16x16x32_f16(ah, bh3, acc3, 0, 0, 0);
  }

  const int K = topk_p[0];
  const bool doMask = (K > 0 && K < N_E);
  const float b2v0 = b2[c], b2v1 = b2[16 + c], b2v2 = b2[32 + c],
              b2v3 = b2[48 + c];

#pragma unroll
  for (int r = 0; r < 4; ++r) {
    const int row = rowbase + kg * 4 + r;
    float* lg = out_logits + (size_t)row * N_E;
    float* mk = out_masked + (size_t)row * N_E;
    float* pb = out_probs  + (size_t)row * N_E;

    const float v0 = acc0[r] + b2v0;
    const float v1 = acc1[r] + b2v1;
    const float v2 = acc2[r] + b2v2;
    const float v3 = acc3[r] + b2v3;
    lg[c] = v0; lg[16 + c] = v1; lg[32 + c] = v2; lg[48 + c] = v3;

    // ---- top-k (argmax K times over 16 lanes x 4 frags, min-idx ties) ----
    bool s0 = true, s1 = true, s2 = true, s3 = true;
    if (doMask) {
      s0 = s1 = s2 = s3 = false;
      float c0 = v0, c1 = v1, c2 = v2, c3 = v3;
      for (int it = 0; it < K; ++it) {
        float m = c0; int mi = c;                 // expert idx 0*16+c
        if (c1 > m) { m = c1; mi = 16 + c; }
        if (c2 > m) { m = c2; mi = 32 + c; }
        if (c3 > m) { m = c3; mi = 48 + c; }
#pragma unroll
        for (int off = 1; off <= 8; off <<= 1) {
          const float om = __shfl_xor(m, off);
          const int   oi = __shfl_xor(mi, off);
          if (om > m || (om == m && oi < mi)) { m = om; mi = oi; }
        }
        if ((mi & 15) == c) {
          const int f = mi >> 4;
          s0 = s0 || (f == 0); c0 = (f == 0) ? -FLT_MAX : c0;
          s1 = s1 || (f == 1); c1 = (f == 1) ? -FLT_MAX : c1;
          s2 = s2 || (f == 2); c2 = (f == 2) ? -FLT_MAX : c2;
          s3 = s3 || (f == 3); c3 = (f == 3) ? -FLT_MAX : c3;
        }
      }
    }
    const float m0 = s0 ? v0 : NEG_INF_VAL;
    const float m1 = s1 ? v1 : NEG_INF_VAL;
    const float m2 = s2 ? v2 : NEG_INF_VAL;
    const float m3 = s3 ? v3 : NEG_INF_VAL;
    mk[c] = m0; mk[16 + c] = m1; mk[32 + c] = m2; mk[48 + c] = m3;

    // ---- softmax over masked ----
    float mx = fmaxf(fmaxf(m0, m1), fmaxf(m2, m3));
#pragma unroll
    for (int off = 1; off <= 8; off <<= 1) mx = fmaxf(mx, __shfl_xor(mx, off));
    const float e0 = __expf(m0 - mx);
    const float e1 = __expf(m1 - mx);
    const float e2 = __expf(m2 - mx);
    const float e3 = __expf(m3 - mx);
    float sm = e0 + e1 + e2 + e3;
#pragma unroll
    for (int off = 1; off <= 8; off <<= 1) sm += __shfl_xor(sm, off);
    const float inv = 1.0f / sm;
    pb[c] = e0 * inv; pb[16 + c] = e1 * inv; pb[32 + c] = e2 * inv;
    pb[48 + c] = e3 * inv;
  }
}

// ============================== launcher ===================================
extern "C" void kernel_launch(void* const* d_in, const int* in_sizes, int n_in,
                              void* d_out, int out_size, void* d_ws,
                              size_t ws_size, hipStream_t stream) {
  const float* x  = (const float*)d_in[0];
  const float* w1 = (const float*)d_in[1];
  const float* b1 = (const float*)d_in[2];
  const float* w2 = (const float*)d_in[3];
  const float* b2 = (const float*)d_in[4];
  const int* topk = (const int*)d_in[5];

  char* ws = (char*)d_ws;
  _Float16* whT  = (_Float16*)(ws);                  // 512 KB
  _Float16* wlT  = (_Float16*)(ws + 524288);         // 512 KB
  _Float16* w2hT = (_Float16*)(ws + 1048576);        // 32 KB
  _Float16* w2lT = (_Float16*)(ws + 1081344);        // 32 KB
  float*    hbuf = (float*)(ws + 1114112);           // 33.5 MB

  float* out_logits = (float*)d_out;
  float* out_masked = out_logits + (size_t)N_ROWS * N_E;
  float* out_probs  = out_masked + (size_t)N_ROWS * N_E;

  split_weights_kernel<<<(D_IN * D_H + D_H * N_E) / 256, 256, 0, stream>>>(
      w1, w2, whT, wlT, w2hT, w2lT);

  gemm1_mfma_kernel<<<(N_ROWS / BM) * (D_H / BN), 512, 0, stream>>>(
      x, whT, wlT, b1, hbuf);

  router_mfma_kernel<<<N_ROWS / 64, 256, 0, stream>>>(
      hbuf, w2hT, w2lT, b2, topk, out_logits, out_masked, out_probs);
}